// Round 6
// baseline (259.337 us; speedup 1.0000x reference)
//
#include <hip/hip_runtime.h>
#include <stdint.h>
#include <stddef.h>

using f16 = _Float16;
typedef __attribute__((ext_vector_type(8))) _Float16 f16x8;
typedef __attribute__((ext_vector_type(4))) float f32x4;

// ---------------------------------------------------------------------------
__device__ __forceinline__ void async_copy16(const f16* g, f16* l) {
    __builtin_amdgcn_global_load_lds(
        (const __attribute__((address_space(1))) void*)g,
        (__attribute__((address_space(3))) void*)l, 16, 0, 0);
}

// ---------------------------------------------------------------------------
// Weight prep, 6144 blocks: z<3 f16 convert (Wq,Wk,Wv), z>=3 f16 transpose
// (Wo, mlp_in, mlp_out).
__global__ __launch_bounds__(256)
void prep_w(const float* __restrict__ w0, const float* __restrict__ w1,
            const float* __restrict__ w2, const float* __restrict__ w3,
            const float* __restrict__ w4, const float* __restrict__ w5,
            f16* o0, f16* o1, f16* o2, f16* o3, f16* o4, f16* o5, int D) {
    __shared__ float tile[32][33];
    const int tx = threadIdx.x & 31, ty = threadIdx.x >> 5;
    const int b = blockIdx.x;
    const int z = b >> 10, r = b & 1023;
    const float* in = z == 0 ? w0 : z == 1 ? w1 : z == 2 ? w2 : z == 3 ? w3 : z == 4 ? w4 : w5;
    f16* out = z == 0 ? o0 : z == 1 ? o1 : z == 2 ? o2 : z == 3 ? o3 : z == 4 ? o4 : o5;
    const int c0 = (r & 31) * 32, r0 = (r >> 5) * 32;
    if (z < 3) {
#pragma unroll
        for (int j = 0; j < 4; j++) {
            size_t idx = (size_t)(r0 + ty + j * 8) * D + c0 + tx;
            out[idx] = (f16)in[idx];
        }
    } else {
#pragma unroll
        for (int j = 0; j < 4; j++)
            tile[ty + j * 8][tx] = in[(size_t)(r0 + ty + j * 8) * D + c0 + tx];
        __syncthreads();
#pragma unroll
        for (int j = 0; j < 4; j++)
            out[(size_t)(c0 + ty + j * 8) * D + r0 + tx] = (f16)tile[tx][ty + j * 8];
    }
}

// ---------------------------------------------------------------------------
// 64x64x128-step fp16 GEMM body, double-buffered+swizzled (tiny stage only).
__device__ __forceinline__ void body64db(
    f16* lds, const f16* __restrict__ A, const f16* __restrict__ B,
    f16* __restrict__ Ch, int m0, int n0, int N, int K, int lda) {
    const int t = threadIdx.x;
    const int lane = t & 63, wave = t >> 6;
    const int wm = (wave >> 1) * 32, wn = (wave & 1) * 32;
    const int lm = lane & 15, lq = lane >> 4;
    const int srow = t >> 2;
    const int gs = ((t & 3) ^ ((srow >> 1) & 3)) * 8;
    const int rs = (lq ^ ((lm >> 1) & 3)) * 8;

    auto stage = [&](f16* buf, int k0) {
#pragma unroll
        for (int r = 0; r < 4; r++)
            async_copy16(A + (size_t)(m0 + srow) * lda + k0 + r * 32 + gs,
                         buf + r * 2048 + t * 8);
#pragma unroll
        for (int r = 0; r < 4; r++)
            async_copy16(B + (size_t)(n0 + srow) * K + k0 + r * 32 + gs,
                         buf + 8192 + r * 2048 + t * 8);
    };

    f32x4 acc[2][2] = {};
    stage(lds, 0);
    __syncthreads();
    int cur = 0;
    for (int k0 = 0; k0 < K; k0 += 128) {
        f16* cb = lds + cur * 16384;
        if (k0 + 128 < K) stage(lds + (cur ^ 1) * 16384, k0 + 128);
#pragma unroll
        for (int kk = 0; kk < 4; kk++) {
            f16x8 af[2], bf[2];
#pragma unroll
            for (int i = 0; i < 2; i++)
                af[i] = *(const f16x8*)&cb[kk * 2048 + (wm + i * 16 + lm) * 32 + rs];
#pragma unroll
            for (int j = 0; j < 2; j++)
                bf[j] = *(const f16x8*)&cb[8192 + kk * 2048 + (wn + j * 16 + lm) * 32 + rs];
#pragma unroll
            for (int i = 0; i < 2; i++)
#pragma unroll
                for (int j = 0; j < 2; j++)
                    acc[i][j] = __builtin_amdgcn_mfma_f32_16x16x32_f16(
                        af[i], bf[j], acc[i][j], 0, 0, 0);
        }
        __syncthreads();
        cur ^= 1;
    }

#pragma unroll
    for (int i = 0; i < 2; i++) {
        const int row = m0 + wm + i * 16 + lq * 4;
#pragma unroll
        for (int j = 0; j < 2; j++) {
            const int col = n0 + wn + j * 16 + lm;
            f32x4 v = acc[i][j];
#pragma unroll
            for (int r = 0; r < 4; r++)
                Ch[(size_t)(row + r) * N + col] = (f16)v[r];
        }
    }
}

// ---------------------------------------------------------------------------
// Fused: X-transpose (blocks 0..4095) ++ tiny GT/HT GEMMs (4096..4607).
__global__ __launch_bounds__(256, 2)
void prepx_tiny(const float* __restrict__ X, f16* __restrict__ Xth,
                const f16* Wkh, const f16* Wqh, f16* GT,
                const f16* Wot, const f16* Wvh, f16* HT, int D, int NT) {
    __shared__ alignas(16) f16 smem[32768];
    int b = blockIdx.x;
    if (b < 4096) {
        float* tile = (float*)smem;  // [32][33]
        const int tx = threadIdx.x & 31, ty = threadIdx.x >> 5;
        const int c0 = (b & 127) * 32, r0 = (b >> 7) * 32;  // c over NT, r over D
#pragma unroll
        for (int j = 0; j < 4; j++)
            tile[(ty + j * 8) * 33 + tx] = X[(size_t)(r0 + ty + j * 8) * NT + c0 + tx];
        __syncthreads();
#pragma unroll
        for (int j = 0; j < 4; j++)
            Xth[(size_t)(c0 + ty + j * 8) * D + r0 + tx] = (f16)tile[tx * 33 + ty + j * 8];
        return;
    }
    b -= 4096;  // 0..511
    if (b < 256)
        body64db(smem, Wkh, Wqh, GT, (b >> 4) * 64, (b & 15) * 64, 1024, 1024, 1024);
    else {
        const int r = b - 256;
        body64db(smem, Wot, Wvh, HT, (r >> 4) * 64, (r & 15) * 64, 1024, 1024, 1024);
    }
}

// ---------------------------------------------------------------------------
// Causal softmax over f16 A rows IN-PLACE (pitch N).
__global__ __launch_bounds__(256)
void softmax_rows(f16* __restrict__ A, int N) {
    const int row = blockIdx.x, len = row + 1;
    const int lim = ((row >> 7) + 1) << 7;
    f16* a = A + (size_t)row * N;
    __shared__ float red[256];
    const int t = threadIdx.x;

    float v[16];
    float mx = -1e30f;
#pragma unroll
    for (int j = 0; j < 2; j++) {
        const int c = (t + j * 256) * 8;
        if (c < len) {
            f16x8 x = *(const f16x8*)(a + c);
#pragma unroll
            for (int e = 0; e < 8; e++) {
                float f = (c + e < len) ? (float)x[e] : -1e30f;
                v[j * 8 + e] = f;
                mx = fmaxf(mx, f);
            }
        } else {
#pragma unroll
            for (int e = 0; e < 8; e++) v[j * 8 + e] = -1e30f;
        }
    }
    red[t] = mx; __syncthreads();
    for (int o = 128; o > 0; o >>= 1) { if (t < o) red[t] = fmaxf(red[t], red[t + o]); __syncthreads(); }
    mx = red[0]; __syncthreads();

    float sum = 0.f;
#pragma unroll
    for (int k = 0; k < 16; k++) {
        float e = (v[k] > -1e29f) ? __expf(v[k] - mx) : 0.0f;
        v[k] = e;
        sum += e;
    }
    red[t] = sum; __syncthreads();
    for (int o = 128; o > 0; o >>= 1) { if (t < o) red[t] += red[t + o]; __syncthreads(); }
    const float inv = 1.0f / red[0];
#pragma unroll
    for (int j = 0; j < 2; j++) {
        const int c = (t + j * 256) * 8;
        if (c < lim) {
            f16x8 o8;
#pragma unroll
            for (int e = 0; e < 8; e++) o8[e] = (f16)(v[j * 8 + e] * inv);
            *(f16x8*)(a + c) = o8;
        }
    }
}

// ---------------------------------------------------------------------------
// Swizzle (proven, conflicts 0): LDS [kk][row][32] f16; k-group g of row r
// stored at slot g ^ ((r>>1)&3); applied to global source col (gs) and
// ds_read slot (rs); gload_lds dest stays linear.
//
// m97 structure (874-912 TF proven): SINGLE-buffered LDS, plain
// stage -> __syncthreads -> compute -> __syncthreads loop. The implicit
// vmcnt(0) drain before the barrier is hidden by the THIRD co-resident
// block (m114 cross-block TLP); dbuf at 64 KB cuts to 2 blocks/CU and
// loses more than the pipeline gains (m132: 508 TF).
// ---------------------------------------------------------------------------

// 128x128 tile, BK=64, 4 waves each owning 64x64 (acc 4x4). Single-buffered
// 32 KB LDS -> 3 blocks/CU with VGPR<=170. MODE 0 only.
__device__ __forceinline__ void body128sq(
    f16* lds, const f16* __restrict__ A, const f16* __restrict__ B,
    f16* __restrict__ Ch, int m0, int n0, int N, int K, int lda) {
    const int t = threadIdx.x;
    const int lane = t & 63, wave = t >> 6;
    const int wm = (wave >> 1) * 64, wn = (wave & 1) * 64;
    const int lm = lane & 15, lq = lane >> 4;
    const int srow = t >> 2;
    const int gs = ((t & 3) ^ ((srow >> 1) & 3)) * 8;
    const int rs = (lq ^ ((lm >> 1) & 3)) * 8;

    f32x4 acc[4][4] = {};

    const int NS = K >> 6;
    for (int s = 0; s < NS; s++) {
        const int k0 = s << 6;
        // stage: 8 gload_lds per wave (4 A + 4 B); dest = uniform + t*8 f16.
#pragma unroll
        for (int r = 0; r < 4; r++)
            async_copy16(A + (size_t)(m0 + (r & 1) * 64 + srow) * lda + k0 + (r >> 1) * 32 + gs,
                         lds + r * 2048 + t * 8);
#pragma unroll
        for (int r = 0; r < 4; r++)
            async_copy16(B + (size_t)(n0 + (r & 1) * 64 + srow) * K + k0 + (r >> 1) * 32 + gs,
                         lds + 8192 + r * 2048 + t * 8);
        __syncthreads();
#pragma unroll
        for (int kk = 0; kk < 2; kk++) {
            f16x8 af[4], bf[4];
#pragma unroll
            for (int i = 0; i < 4; i++)
                af[i] = *(const f16x8*)&lds[kk * 4096 + (wm + i * 16 + lm) * 32 + rs];
#pragma unroll
            for (int j = 0; j < 4; j++)
                bf[j] = *(const f16x8*)&lds[8192 + kk * 4096 + (wn + j * 16 + lm) * 32 + rs];
#pragma unroll
            for (int i = 0; i < 4; i++)
#pragma unroll
                for (int j = 0; j < 4; j++)
                    acc[i][j] = __builtin_amdgcn_mfma_f32_16x16x32_f16(
                        af[i], bf[j], acc[i][j], 0, 0, 0);
        }
        if (s + 1 < NS) __syncthreads();
    }

    // C/D layout: col = lane&15, row = (lane>>4)*4 + reg.
#pragma unroll
    for (int i = 0; i < 4; i++) {
        const int row = m0 + wm + i * 16 + lq * 4;
#pragma unroll
        for (int j = 0; j < 4; j++) {
            const int col = n0 + wn + j * 16 + lm;
            f32x4 v = acc[i][j];
#pragma unroll
            for (int r = 0; r < 4; r++)
                Ch[(size_t)(row + r) * N + col] = (f16)v[r];
        }
    }
}

// ---------------------------------------------------------------------------
// 128x64 tile, BK=64, 4 waves each 64x32 (acc 4x2). Single-buffered 24 KB.
// MODE 0: Ch = f16(acc)
// MODE 2: Ch = f16(acc + residH)
// MODE 3: Ch = f16(relu(acc))
// MODE 4: Cf[col*M + row] = acc + residH[row*N + col]  (transposed store)
template <int MODE>
__device__ __forceinline__ void body_nar(
    f16* lds, const f16* __restrict__ A, const f16* __restrict__ B,
    float* __restrict__ Cf, f16* __restrict__ Ch, const f16* __restrict__ resid,
    int m0, int n0, int M, int N, int K, int lda, int Keff) {
    constexpr int ASZ = 128 * 64;   // 8192 f16
    const int t = threadIdx.x;
    const int lane = t & 63, wave = t >> 6;
    const int wm = (wave >> 1) * 64, wn = (wave & 1) * 32;
    const int lm = lane & 15, lq = lane >> 4;
    const int srow = t >> 2;
    const int gs = ((t & 3) ^ ((srow >> 1) & 3)) * 8;
    const int rs = (lq ^ ((lm >> 1) & 3)) * 8;

    f32x4 acc[4][2] = {};

    const int NS = Keff >> 6;
    for (int s = 0; s < NS; s++) {
        const int k0 = s << 6;
#pragma unroll
        for (int r = 0; r < 4; r++)
            async_copy16(A + (size_t)(m0 + (r & 1) * 64 + srow) * lda + k0 + (r >> 1) * 32 + gs,
                         lds + r * 2048 + t * 8);
#pragma unroll
        for (int r = 0; r < 2; r++)
            async_copy16(B + (size_t)(n0 + srow) * K + k0 + r * 32 + gs,
                         lds + ASZ + r * 2048 + t * 8);
        __syncthreads();
#pragma unroll
        for (int kk = 0; kk < 2; kk++) {
            f16x8 af[4], bf[2];
#pragma unroll
            for (int i = 0; i < 4; i++)
                af[i] = *(const f16x8*)&lds[kk * 4096 + (wm + i * 16 + lm) * 32 + rs];
#pragma unroll
            for (int j = 0; j < 2; j++)
                bf[j] = *(const f16x8*)&lds[ASZ + kk * 2048 + (wn + j * 16 + lm) * 32 + rs];
#pragma unroll
            for (int i = 0; i < 4; i++)
#pragma unroll
                for (int j = 0; j < 2; j++)
                    acc[i][j] = __builtin_amdgcn_mfma_f32_16x16x32_f16(
                        af[i], bf[j], acc[i][j], 0, 0, 0);
        }
        if (s + 1 < NS) __syncthreads();
    }

#pragma unroll
    for (int i = 0; i < 4; i++) {
        const int row = m0 + wm + i * 16 + lq * 4;
#pragma unroll
        for (int j = 0; j < 2; j++) {
            const int col = n0 + wn + j * 16 + lm;
            f32x4 v = acc[i][j];
#pragma unroll
            for (int r = 0; r < 4; r++) {
                if (MODE == 0) {
                    Ch[(size_t)(row + r) * N + col] = (f16)v[r];
                } else if (MODE == 2) {
                    float o = v[r] + (float)resid[(size_t)(row + r) * N + col];
                    Ch[(size_t)(row + r) * N + col] = (f16)o;
                } else if (MODE == 3) {
                    Ch[(size_t)(row + r) * N + col] = (f16)fmaxf(v[r], 0.0f);
                } else {
                    float o = v[r] + (float)resid[(size_t)(row + r) * N + col];
                    Cf[(size_t)col * M + (row + r)] = o;
                }
            }
        }
    }
}

// ---------------------------------------------------------------------------
// Q' = Xt*G^T [4096,1024,1024], 128x64 tiles, 512 blocks.
__global__ __launch_bounds__(256, 3)
void midq(const f16* Xth, const f16* GT, f16* Qp) {
    __shared__ alignas(16) f16 smem[12288];
    const int x = blockIdx.x & 7, s = blockIdx.x >> 3;  // 0..63
    const int m = x + 8 * (s >> 4), n = s & 15;
    body_nar<0>(smem, Xth, GT, nullptr, Qp, nullptr,
                m * 128, n * 64, 4096, 1024, 1024, 1024, 1024);
}

// ---------------------------------------------------------------------------
// Fused: scores (lower triangle, blocks 0..527) ++ RHt = HT*Xt^T (528..783).
// Single-buffered 32 KB body -> 3 blocks/CU.
__global__ __launch_bounds__(256, 3)
void scores_midrh(const f16* Qp, const f16* Xth, f16* Af,
                  const f16* HT, f16* RHt) {
    __shared__ alignas(16) f16 smem[16384];
    int b = blockIdx.x;
    if (b < 528) {
        const int x = b & 7;
        int s = b >> 3;  // 0..65
        int m = 0, n = 0;
#pragma unroll
        for (int q = 3; q >= 0; q--) {
            const int mm = 8 * q + ((q & 1) ? 7 - x : x);
            if (s < mm + 1) { m = mm; n = s; break; }
            s -= mm + 1;
        }
        body128sq(smem, Qp, Xth, Af, m * 128, n * 128, 4096, 1024, 1024);
    } else {
        const int r = b - 528;  // 0..255
        const int x = r & 7;
        const int s = r >> 3;   // 0..31
        const int n = x + 8 * (s >> 3), m = s & 7;
        body128sq(smem, HT, Xth, RHt, m * 128, n * 128, 4096, 1024, 1024);
    }
}

// Narrow GEMMs [M=4096, N=1024], 128x64 tiles, 512 blocks.
// CAUSAL: q-permutation {3,2,0,1} + zigzag makes the static pair
// (block c, block c+256) on one CU sum to exactly 33*128 K-elems per CU.
template <int MODE, bool CAUSAL_K>
__global__ __launch_bounds__(256, 3)
void gemm_nar(const f16* __restrict__ A, const f16* __restrict__ B,
              float* __restrict__ Cf, f16* __restrict__ Ch,
              const f16* __restrict__ resid, int M, int N, int K, int lda) {
    __shared__ alignas(16) f16 smem[12288];
    const int x = blockIdx.x & 7, s = blockIdx.x >> 3;  // s in 0..63
    const int qs = s >> 4, n = s & 15;
    int m;
    if (CAUSAL_K) {
        const int q = (qs == 0) ? 3 : (qs == 1) ? 2 : (qs == 2) ? 0 : 1;
        m = 8 * q + ((q & 1) ? 7 - x : x);
    } else {
        m = x + 8 * qs;
    }
    const int m0 = m * 128, n0 = n * 64;
    int Keff = K;
    if (CAUSAL_K) {
        Keff = m0 + 128;
        if (Keff > K) Keff = K;
    }
    body_nar<MODE>(smem, A, B, Cf, Ch, resid,
                   m0, n0, M, N, K, lda, Keff);
}

// ---------------------------------------------------------------------------
extern "C" void kernel_launch(void* const* d_in, const int* in_sizes, int n_in,
                              void* d_out, int out_size, void* d_ws, size_t ws_size,
                              hipStream_t stream) {
    const int D = 1024, NT = 4096;
    const float* X = (const float*)d_in[0];
    const float* W[6] = {(const float*)d_in[1], (const float*)d_in[2],
                         (const float*)d_in[3], (const float*)d_in[4],
                         (const float*)d_in[5], (const float*)d_in[6]};
    char* ws = (char*)d_ws;
    auto MB = [](size_t x) { return x << 20; };

    // Workspace (80 MB peak):
    f16*   Xth  = (f16*)(ws + MB(0));      // [NT][D] (also f16 residual)
    f16*   Wqh  = (f16*)(ws + MB(8));
    f16*   Wkh  = (f16*)(ws + MB(10));
    f16*   Wvh  = (f16*)(ws + MB(12));
    f16*   Wot  = (f16*)(ws + MB(14));
    f16*   W4t  = (f16*)(ws + MB(16));
    f16*   W5t  = (f16*)(ws + MB(18));
    f16*   GT   = (f16*)(ws + MB(20));     // [D][D]
    f16*   HT   = (f16*)(ws + MB(22));     // [D][D]
    f16*   Qp   = (f16*)(ws + MB(24));     // [NT][D] (dead after scores)
    f16*   Af   = (f16*)(ws + MB(32));     // [NT][NT] f16 scores -> softmax A
    f16*   RHt  = (f16*)(ws + MB(64));     // [D][NT]
    f16*   Y1h  = (f16*)(ws + MB(72));     // [NT][D]
    f16*   hb   = (f16*)(ws + MB(24));     // over Qp (dead)
    float* outF = (float*)d_out;           // [D][NT]

    // 1. Weight prep (convert + transpose).
    prep_w<<<6144, 256, 0, stream>>>(W[0], W[1], W[2], W[3], W[4], W[5],
                                     Wqh, Wkh, Wvh, Wot, W4t, W5t, D);

    // 2. X-transpose ++ GT = Wk*Wq^T ++ HT = Wo^T*Wv^T (fused, independent).
    prepx_tiny<<<4608, 256, 0, stream>>>(X, Xth, Wkh, Wqh, GT, Wot, Wvh, HT,
                                         D, NT);

    // 3. Q' = Xt*G^T (single-buffered narrow).
    midq<<<512, 256, 0, stream>>>(Xth, GT, Qp);

    // 4. Scores (lower triangle) ++ RHt = HT*Xt^T (fused, single-buffered).
    scores_midrh<<<784, 256, 0, stream>>>(Qp, Xth, Af, HT, RHt);

    // 5. Softmax in-place on f16 A (pitch NT).
    softmax_rows<<<NT, 256, 0, stream>>>(Af, NT);

    // 6. Y1 = Xt + A@RH (causal-K truncation, CU-pair-balanced).
    gemm_nar<2, true><<<512, 256, 0, stream>>>(
        Af, RHt, nullptr, Y1h, Xth, NT, D, NT, NT);

    // 7. h = relu(Y1 @ mlp_in).
    gemm_nar<3, false><<<512, 256, 0, stream>>>(
        Y1h, W4t, nullptr, hb, nullptr, NT, D, D, D);

    // 8. out = (Y1 + h @ mlp_out)^T.
    gemm_nar<4, false><<<512, 256, 0, stream>>>(
        hb, W5t, outF, nullptr, Y1h, NT, D, D, D);
}

// Round 7
// 244.605 us; speedup vs baseline: 1.0602x; 1.0602x over previous
//
#include <hip/hip_runtime.h>
#include <stdint.h>
#include <stddef.h>

using f16 = _Float16;
typedef __attribute__((ext_vector_type(8))) _Float16 f16x8;
typedef __attribute__((ext_vector_type(4))) float f32x4;

// ---------------------------------------------------------------------------
__device__ __forceinline__ void async_copy16(const f16* g, f16* l) {
    __builtin_amdgcn_global_load_lds(
        (const __attribute__((address_space(1))) void*)g,
        (__attribute__((address_space(3))) void*)l, 16, 0, 0);
}

template <int N>
__device__ __forceinline__ void wait_vmcnt() {
    if constexpr (N == 0)       asm volatile("s_waitcnt vmcnt(0)" ::: "memory");
    else if constexpr (N == 6)  asm volatile("s_waitcnt vmcnt(6)" ::: "memory");
    else if constexpr (N == 8)  asm volatile("s_waitcnt vmcnt(8)" ::: "memory");
    else if constexpr (N == 12) asm volatile("s_waitcnt vmcnt(12)" ::: "memory");
}

__device__ __forceinline__ void hard_barrier() {
    __builtin_amdgcn_sched_barrier(0);
    __builtin_amdgcn_s_barrier();
    __builtin_amdgcn_sched_barrier(0);
}

// ---------------------------------------------------------------------------
// Weight prep, 4096 blocks: z<3 f16 convert (Wq,Wk,Wv), z==3 Wo transpose.
// (W4/W5 transposes moved into prepx_tiny — independent of tiny's inputs.)
__global__ __launch_bounds__(256)
void prep_w(const float* __restrict__ w0, const float* __restrict__ w1,
            const float* __restrict__ w2, const float* __restrict__ w3,
            f16* o0, f16* o1, f16* o2, f16* o3, int D) {
    __shared__ float tile[32][33];
    const int tx = threadIdx.x & 31, ty = threadIdx.x >> 5;
    const int b = blockIdx.x;
    const int z = b >> 10, r = b & 1023;
    const float* in = z == 0 ? w0 : z == 1 ? w1 : z == 2 ? w2 : w3;
    f16* out = z == 0 ? o0 : z == 1 ? o1 : z == 2 ? o2 : o3;
    const int c0 = (r & 31) * 32, r0 = (r >> 5) * 32;
    if (z < 3) {
#pragma unroll
        for (int j = 0; j < 4; j++) {
            size_t idx = (size_t)(r0 + ty + j * 8) * D + c0 + tx;
            out[idx] = (f16)in[idx];
        }
    } else {
#pragma unroll
        for (int j = 0; j < 4; j++)
            tile[ty + j * 8][tx] = in[(size_t)(r0 + ty + j * 8) * D + c0 + tx];
        __syncthreads();
#pragma unroll
        for (int j = 0; j < 4; j++)
            out[(size_t)(c0 + ty + j * 8) * D + r0 + tx] = (f16)tile[tx][ty + j * 8];
    }
}

// ---------------------------------------------------------------------------
// 64x64x128-step fp16 GEMM body, double-buffered+swizzled (tiny stage only).
__device__ __forceinline__ void body64db(
    f16* lds, const f16* __restrict__ A, const f16* __restrict__ B,
    f16* __restrict__ Ch, int m0, int n0, int N, int K, int lda) {
    const int t = threadIdx.x;
    const int lane = t & 63, wave = t >> 6;
    const int wm = (wave >> 1) * 32, wn = (wave & 1) * 32;
    const int lm = lane & 15, lq = lane >> 4;
    const int srow = t >> 2;
    const int gs = ((t & 3) ^ ((srow >> 1) & 3)) * 8;
    const int rs = (lq ^ ((lm >> 1) & 3)) * 8;

    auto stage = [&](f16* buf, int k0) {
#pragma unroll
        for (int r = 0; r < 4; r++)
            async_copy16(A + (size_t)(m0 + srow) * lda + k0 + r * 32 + gs,
                         buf + r * 2048 + t * 8);
#pragma unroll
        for (int r = 0; r < 4; r++)
            async_copy16(B + (size_t)(n0 + srow) * K + k0 + r * 32 + gs,
                         buf + 8192 + r * 2048 + t * 8);
    };

    f32x4 acc[2][2] = {};
    stage(lds, 0);
    __syncthreads();
    int cur = 0;
    for (int k0 = 0; k0 < K; k0 += 128) {
        f16* cb = lds + cur * 16384;
        if (k0 + 128 < K) stage(lds + (cur ^ 1) * 16384, k0 + 128);
#pragma unroll
        for (int kk = 0; kk < 4; kk++) {
            f16x8 af[2], bf[2];
#pragma unroll
            for (int i = 0; i < 2; i++)
                af[i] = *(const f16x8*)&cb[kk * 2048 + (wm + i * 16 + lm) * 32 + rs];
#pragma unroll
            for (int j = 0; j < 2; j++)
                bf[j] = *(const f16x8*)&cb[8192 + kk * 2048 + (wn + j * 16 + lm) * 32 + rs];
#pragma unroll
            for (int i = 0; i < 2; i++)
#pragma unroll
                for (int j = 0; j < 2; j++)
                    acc[i][j] = __builtin_amdgcn_mfma_f32_16x16x32_f16(
                        af[i], bf[j], acc[i][j], 0, 0, 0);
        }
        __syncthreads();
        cur ^= 1;
    }

#pragma unroll
    for (int i = 0; i < 2; i++) {
        const int row = m0 + wm + i * 16 + lq * 4;
#pragma unroll
        for (int j = 0; j < 2; j++) {
            const int col = n0 + wn + j * 16 + lm;
            f32x4 v = acc[i][j];
#pragma unroll
            for (int r = 0; r < 4; r++)
                Ch[(size_t)(row + r) * N + col] = (f16)v[r];
        }
    }
}

// ---------------------------------------------------------------------------
// Fused: X-transpose (0..4095) ++ W4/W5 transposes (4096..6143) ++
// tiny GT/HT GEMMs (6144..6655). All mutually independent.
__global__ __launch_bounds__(256, 2)
void prepx_tiny(const float* __restrict__ X, f16* __restrict__ Xth,
                const float* __restrict__ w4, const float* __restrict__ w5,
                f16* W4t, f16* W5t,
                const f16* Wkh, const f16* Wqh, f16* GT,
                const f16* Wot, const f16* Wvh, f16* HT, int D, int NT) {
    __shared__ alignas(16) f16 smem[32768];
    int b = blockIdx.x;
    const int tx = threadIdx.x & 31, ty = threadIdx.x >> 5;
    if (b < 4096) {
        float* tile = (float*)smem;  // [32][33]
        const int c0 = (b & 127) * 32, r0 = (b >> 7) * 32;  // c over NT, r over D
#pragma unroll
        for (int j = 0; j < 4; j++)
            tile[(ty + j * 8) * 33 + tx] = X[(size_t)(r0 + ty + j * 8) * NT + c0 + tx];
        __syncthreads();
#pragma unroll
        for (int j = 0; j < 4; j++)
            Xth[(size_t)(c0 + ty + j * 8) * D + r0 + tx] = (f16)tile[tx * 33 + ty + j * 8];
        return;
    }
    b -= 4096;
    if (b < 2048) {  // W4/W5 transpose
        float* tile = (float*)smem;
        const float* in = (b < 1024) ? w4 : w5;
        f16* out = (b < 1024) ? W4t : W5t;
        const int r = b & 1023;
        const int c0 = (r & 31) * 32, r0 = (r >> 5) * 32;
#pragma unroll
        for (int j = 0; j < 4; j++)
            tile[(ty + j * 8) * 33 + tx] = in[(size_t)(r0 + ty + j * 8) * D + c0 + tx];
        __syncthreads();
#pragma unroll
        for (int j = 0; j < 4; j++)
            out[(size_t)(c0 + ty + j * 8) * D + r0 + tx] = (f16)tile[tx * 33 + ty + j * 8];
        return;
    }
    b -= 2048;  // 0..511: tiny GEMMs
    if (b < 256)
        body64db(smem, Wkh, Wqh, GT, (b >> 4) * 64, (b & 15) * 64, 1024, 1024, 1024);
    else {
        const int r = b - 256;
        body64db(smem, Wot, Wvh, HT, (r >> 4) * 64, (r & 15) * 64, 1024, 1024, 1024);
    }
}

// ---------------------------------------------------------------------------
// Swizzle (proven, conflicts 0): LDS [kk][row][32] f16; k-group g of row r
// stored at slot g ^ ((r>>1)&3); applied to global source col (gs) and
// ds_read slot (rs); gload_lds dest stays linear.
// ---------------------------------------------------------------------------

// 128x128 tile, BK=64, 4 waves each 64x64 (acc 4x4). Double-buffered 64 KB,
// counted vmcnt(8) (R5-proven). MODE 0 only. Used by scores.
__device__ __forceinline__ void body128sq_db(
    f16* lds, const f16* __restrict__ A, const f16* __restrict__ B,
    f16* __restrict__ Ch, int m0, int n0, int N, int K, int lda) {
    constexpr int BUF = 16384;
    const int t = threadIdx.x;
    const int lane = t & 63, wave = t >> 6;
    const int wm = (wave >> 1) * 64, wn = (wave & 1) * 64;
    const int lm = lane & 15, lq = lane >> 4;
    const int srow = t >> 2;
    const int gs = ((t & 3) ^ ((srow >> 1) & 3)) * 8;
    const int rs = (lq ^ ((lm >> 1) & 3)) * 8;

    f32x4 acc[4][4] = {};

    auto stage = [&](f16* buf, int k0) {
#pragma unroll
        for (int r = 0; r < 4; r++)
            async_copy16(A + (size_t)(m0 + (r & 1) * 64 + srow) * lda + k0 + (r >> 1) * 32 + gs,
                         buf + r * 2048 + t * 8);
#pragma unroll
        for (int r = 0; r < 4; r++)
            async_copy16(B + (size_t)(n0 + (r & 1) * 64 + srow) * K + k0 + (r >> 1) * 32 + gs,
                         buf + 8192 + r * 2048 + t * 8);
    };

    auto compute = [&](const f16* cb) {
#pragma unroll
        for (int kk = 0; kk < 2; kk++) {
            f16x8 af[4], bf[4];
#pragma unroll
            for (int i = 0; i < 4; i++)
                af[i] = *(const f16x8*)&cb[kk * 4096 + (wm + i * 16 + lm) * 32 + rs];
#pragma unroll
            for (int j = 0; j < 4; j++)
                bf[j] = *(const f16x8*)&cb[8192 + kk * 4096 + (wn + j * 16 + lm) * 32 + rs];
#pragma unroll
            for (int i = 0; i < 4; i++)
#pragma unroll
                for (int j = 0; j < 4; j++)
                    acc[i][j] = __builtin_amdgcn_mfma_f32_16x16x32_f16(
                        af[i], bf[j], acc[i][j], 0, 0, 0);
        }
    };

    const int NS = K >> 6;
    stage(lds, 0);
    for (int s = 0; s < NS; s++) {
        if (s + 1 < NS) {
            stage(lds + ((s + 1) & 1) * BUF, (s + 1) << 6);
            wait_vmcnt<8>();
        } else {
            wait_vmcnt<0>();
        }
        hard_barrier();
        compute(lds + (s & 1) * BUF);
        if (s + 1 < NS) hard_barrier();
    }

#pragma unroll
    for (int i = 0; i < 4; i++) {
        const int row = m0 + wm + i * 16 + lq * 4;
#pragma unroll
        for (int j = 0; j < 4; j++) {
            const int col = n0 + wn + j * 16 + lm;
            f32x4 v = acc[i][j];
#pragma unroll
            for (int r = 0; r < 4; r++)
                Ch[(size_t)(row + r) * N + col] = (f16)v[r];
        }
    }
}

// 128x128 tile, SINGLE-buffered 32 KB (R6-proven correct). Used for midrh
// blocks riding inside the softmax launch — 32 KB keeps softmax occupancy
// at ~5 blocks/CU.
__device__ __forceinline__ void body128sq_1b(
    f16* lds, const f16* __restrict__ A, const f16* __restrict__ B,
    f16* __restrict__ Ch, int m0, int n0, int N, int K, int lda) {
    const int t = threadIdx.x;
    const int lane = t & 63, wave = t >> 6;
    const int wm = (wave >> 1) * 64, wn = (wave & 1) * 64;
    const int lm = lane & 15, lq = lane >> 4;
    const int srow = t >> 2;
    const int gs = ((t & 3) ^ ((srow >> 1) & 3)) * 8;
    const int rs = (lq ^ ((lm >> 1) & 3)) * 8;

    f32x4 acc[4][4] = {};

    const int NS = K >> 6;
    for (int s = 0; s < NS; s++) {
        const int k0 = s << 6;
#pragma unroll
        for (int r = 0; r < 4; r++)
            async_copy16(A + (size_t)(m0 + (r & 1) * 64 + srow) * lda + k0 + (r >> 1) * 32 + gs,
                         lds + r * 2048 + t * 8);
#pragma unroll
        for (int r = 0; r < 4; r++)
            async_copy16(B + (size_t)(n0 + (r & 1) * 64 + srow) * K + k0 + (r >> 1) * 32 + gs,
                         lds + 8192 + r * 2048 + t * 8);
        __syncthreads();
#pragma unroll
        for (int kk = 0; kk < 2; kk++) {
            f16x8 af[4], bf[4];
#pragma unroll
            for (int i = 0; i < 4; i++)
                af[i] = *(const f16x8*)&lds[kk * 4096 + (wm + i * 16 + lm) * 32 + rs];
#pragma unroll
            for (int j = 0; j < 4; j++)
                bf[j] = *(const f16x8*)&lds[8192 + kk * 4096 + (wn + j * 16 + lm) * 32 + rs];
#pragma unroll
            for (int i = 0; i < 4; i++)
#pragma unroll
                for (int j = 0; j < 4; j++)
                    acc[i][j] = __builtin_amdgcn_mfma_f32_16x16x32_f16(
                        af[i], bf[j], acc[i][j], 0, 0, 0);
        }
        if (s + 1 < NS) __syncthreads();
    }

#pragma unroll
    for (int i = 0; i < 4; i++) {
        const int row = m0 + wm + i * 16 + lq * 4;
#pragma unroll
        for (int j = 0; j < 4; j++) {
            const int col = n0 + wn + j * 16 + lm;
            f32x4 v = acc[i][j];
#pragma unroll
            for (int r = 0; r < 4; r++)
                Ch[(size_t)(row + r) * N + col] = (f16)v[r];
        }
    }
}

// ---------------------------------------------------------------------------
// 128x64-tile, BK=64 fp16 GEMM body, PF=2 ring of 3 (R3/R5-proven).
// MODE 0: Ch = f16(acc)
// MODE 2: Ch = f16(acc + residH)
// MODE 3: Ch = f16(relu(acc))
// MODE 4: Cf[col*M + row] = acc + residH[row*N + col]  (transposed store)
template <int MODE>
__device__ __forceinline__ void body_pf2(
    f16* lds, const f16* __restrict__ A, const f16* __restrict__ B,
    float* __restrict__ Cf, f16* __restrict__ Ch, const f16* __restrict__ resid,
    int m0, int n0, int M, int N, int K, int lda, int Keff) {
    constexpr int ASZ = 128 * 64;
    constexpr int BSZ = 64 * 64;
    constexpr int SSZ = ASZ + BSZ;  // 24 KB
    const int t = threadIdx.x;
    const int lane = t & 63, wave = t >> 6;
    const int wm = (wave >> 1) * 64, wn = (wave & 1) * 32;
    const int lm = lane & 15, lq = lane >> 4;
    const int srow = t >> 2;
    const int gs = ((t & 3) ^ ((srow >> 1) & 3)) * 8;
    const int rs = (lq ^ ((lm >> 1) & 3)) * 8;

    f32x4 acc[4][2] = {};

    auto stage = [&](f16* buf, int k0) {
#pragma unroll
        for (int r = 0; r < 4; r++)
            async_copy16(A + (size_t)(m0 + (r & 1) * 64 + srow) * lda + k0 + (r >> 1) * 32 + gs,
                         buf + r * 2048 + t * 8);
#pragma unroll
        for (int r = 0; r < 2; r++)
            async_copy16(B + (size_t)(n0 + srow) * K + k0 + r * 32 + gs,
                         buf + ASZ + r * 2048 + t * 8);
    };

    auto compute = [&](const f16* cb) {
#pragma unroll
        for (int kk = 0; kk < 2; kk++) {
            f16x8 af[4], bf[2];
#pragma unroll
            for (int i = 0; i < 4; i++)
                af[i] = *(const f16x8*)&cb[kk * 4096 + (wm + i * 16 + lm) * 32 + rs];
#pragma unroll
            for (int j = 0; j < 2; j++)
                bf[j] = *(const f16x8*)&cb[ASZ + kk * 2048 + (wn + j * 16 + lm) * 32 + rs];
#pragma unroll
            for (int i = 0; i < 4; i++)
#pragma unroll
                for (int j = 0; j < 2; j++)
                    acc[i][j] = __builtin_amdgcn_mfma_f32_16x16x32_f16(
                        af[i], bf[j], acc[i][j], 0, 0, 0);
        }
    };

    f16 *pa = lds, *pb = lds + SSZ, *pc = lds + 2 * SSZ;
    stage(pa, 0);
    stage(pb, 64);
    const int NS = Keff >> 6;
    for (int s = 0; s < NS; s++) {
        const int k2 = (s + 2) << 6;
        if (k2 < Keff) {
            stage(pc, k2);
            wait_vmcnt<12>();
        } else if (s + 1 < NS) {
            wait_vmcnt<6>();
        } else {
            wait_vmcnt<0>();
        }
        hard_barrier();
        compute(pa);
        hard_barrier();
        f16* tp = pa; pa = pb; pb = pc; pc = tp;
    }

#pragma unroll
    for (int i = 0; i < 4; i++) {
        const int row = m0 + wm + i * 16 + lq * 4;
#pragma unroll
        for (int j = 0; j < 2; j++) {
            const int col = n0 + wn + j * 16 + lm;
            f32x4 v = acc[i][j];
#pragma unroll
            for (int r = 0; r < 4; r++) {
                if (MODE == 0) {
                    Ch[(size_t)(row + r) * N + col] = (f16)v[r];
                } else if (MODE == 2) {
                    float o = v[r] + (float)resid[(size_t)(row + r) * N + col];
                    Ch[(size_t)(row + r) * N + col] = (f16)o;
                } else if (MODE == 3) {
                    Ch[(size_t)(row + r) * N + col] = (f16)fmaxf(v[r], 0.0f);
                } else {
                    float o = v[r] + (float)resid[(size_t)(row + r) * N + col];
                    Cf[(size_t)col * M + (row + r)] = o;
                }
            }
        }
    }
}

// ---------------------------------------------------------------------------
// Q' = Xt*G^T [4096,1024,1024], 128x64 PF2 tiles, 512 blocks.
__global__ __launch_bounds__(256, 2)
void midq(const f16* Xth, const f16* GT, f16* Qp) {
    __shared__ alignas(16) f16 smem[36864];
    const int x = blockIdx.x & 7, s = blockIdx.x >> 3;  // 0..63
    const int m = x + 8 * (s >> 4), n = s & 15;
    body_pf2<0>(smem, Xth, GT, nullptr, Qp, nullptr,
                m * 128, n * 64, 4096, 1024, 1024, 1024, 1024);
}

// ---------------------------------------------------------------------------
// Scores over the lower triangle, 128² dbuf-counted tiles, 528 blocks
// (8 residues x 66). Residue x owns row-blocks {x,15-x,16+x,31-x}.
__global__ __launch_bounds__(256, 2)
void scores_tri(const f16* Qp, const f16* Xth, f16* Af) {
    __shared__ alignas(16) f16 smem[32768];
    const int x = blockIdx.x & 7;
    int s = blockIdx.x >> 3;  // 0..65
    int m = 0, n = 0;
#pragma unroll
    for (int q = 3; q >= 0; q--) {
        const int mm = 8 * q + ((q & 1) ? 7 - x : x);
        if (s < mm + 1) { m = mm; n = s; break; }
        s -= mm + 1;
    }
    body128sq_db(smem, Qp, Xth, Af, m * 128, n * 128, 4096, 1024, 1024);
}

// ---------------------------------------------------------------------------
// Fused: causal softmax rows (blocks 0..4095, BW-bound) ++ RHt = HT*Xt^T
// (4096..4351, MFMA-bound, single-buffered 32 KB so softmax keeps ~5
// blocks/CU). Different pipes -> superposition (m114).
__global__ __launch_bounds__(256)
void softmax_midrh(f16* __restrict__ A, int N,
                   const f16* HT, const f16* Xth, f16* RHt) {
    __shared__ alignas(16) f16 smem[16384];
    int b = blockIdx.x;
    if (b >= 4096) {
        const int r = b - 4096;  // 0..255
        const int x = r & 7;
        const int s = r >> 3;    // 0..31
        const int n = x + 8 * (s >> 3), m = s & 7;
        body128sq_1b(smem, HT, Xth, RHt, m * 128, n * 128, 4096, 1024, 1024);
        return;
    }
    const int row = b, len = row + 1;
    const int lim = ((row >> 7) + 1) << 7;
    f16* a = A + (size_t)row * N;
    float* red = (float*)smem;  // [256]
    const int t = threadIdx.x;

    float v[16];
    float mx = -1e30f;
#pragma unroll
    for (int j = 0; j < 2; j++) {
        const int c = (t + j * 256) * 8;
        if (c < len) {
            f16x8 x = *(const f16x8*)(a + c);
#pragma unroll
            for (int e = 0; e < 8; e++) {
                float f = (c + e < len) ? (float)x[e] : -1e30f;
                v[j * 8 + e] = f;
                mx = fmaxf(mx, f);
            }
        } else {
#pragma unroll
            for (int e = 0; e < 8; e++) v[j * 8 + e] = -1e30f;
        }
    }
    red[t] = mx; __syncthreads();
    for (int o = 128; o > 0; o >>= 1) { if (t < o) red[t] = fmaxf(red[t], red[t + o]); __syncthreads(); }
    mx = red[0]; __syncthreads();

    float sum = 0.f;
#pragma unroll
    for (int k = 0; k < 16; k++) {
        float e = (v[k] > -1e29f) ? __expf(v[k] - mx) : 0.0f;
        v[k] = e;
        sum += e;
    }
    red[t] = sum; __syncthreads();
    for (int o = 128; o > 0; o >>= 1) { if (t < o) red[t] += red[t + o]; __syncthreads(); }
    const float inv = 1.0f / red[0];
#pragma unroll
    for (int j = 0; j < 2; j++) {
        const int c = (t + j * 256) * 8;
        if (c < lim) {
            f16x8 o8;
#pragma unroll
            for (int e = 0; e < 8; e++) o8[e] = (f16)(v[j * 8 + e] * inv);
            *(f16x8*)(a + c) = o8;
        }
    }
}

// Narrow GEMMs [M=4096, N=1024], 128x64 PF2 tiles, 512 blocks.
// CAUSAL: q-permutation {3,2,0,1} + zigzag makes the static pair
// (block c, block c+256) on one CU sum to exactly 33*128 K-elems per CU.
template <int MODE, bool CAUSAL_K>
__global__ __launch_bounds__(256, 2)
void gemm_nar(const f16* __restrict__ A, const f16* __restrict__ B,
              float* __restrict__ Cf, f16* __restrict__ Ch,
              const f16* __restrict__ resid, int M, int N, int K, int lda) {
    __shared__ alignas(16) f16 smem[36864];
    const int x = blockIdx.x & 7, s = blockIdx.x >> 3;  // s in 0..63
    const int qs = s >> 4, n = s & 15;
    int m;
    if (CAUSAL_K) {
        const int q = (qs == 0) ? 3 : (qs == 1) ? 2 : (qs == 2) ? 0 : 1;
        m = 8 * q + ((q & 1) ? 7 - x : x);
    } else {
        m = x + 8 * qs;
    }
    const int m0 = m * 128, n0 = n * 64;
    int Keff = K;
    if (CAUSAL_K) {
        Keff = m0 + 128;
        if (Keff > K) Keff = K;
    }
    body_pf2<MODE>(smem, A, B, Cf, Ch, resid,
                   m0, n0, M, N, K, lda, Keff);
}

// ---------------------------------------------------------------------------
extern "C" void kernel_launch(void* const* d_in, const int* in_sizes, int n_in,
                              void* d_out, int out_size, void* d_ws, size_t ws_size,
                              hipStream_t stream) {
    const int D = 1024, NT = 4096;
    const float* X = (const float*)d_in[0];
    const float* W[6] = {(const float*)d_in[1], (const float*)d_in[2],
                         (const float*)d_in[3], (const float*)d_in[4],
                         (const float*)d_in[5], (const float*)d_in[6]};
    char* ws = (char*)d_ws;
    auto MB = [](size_t x) { return x << 20; };

    // Workspace (80 MB peak):
    f16*   Xth  = (f16*)(ws + MB(0));      // [NT][D] (also f16 residual)
    f16*   Wqh  = (f16*)(ws + MB(8));
    f16*   Wkh  = (f16*)(ws + MB(10));
    f16*   Wvh  = (f16*)(ws + MB(12));
    f16*   Wot  = (f16*)(ws + MB(14));
    f16*   W4t  = (f16*)(ws + MB(16));
    f16*   W5t  = (f16*)(ws + MB(18));
    f16*   GT   = (f16*)(ws + MB(20));     // [D][D]
    f16*   HT   = (f16*)(ws + MB(22));     // [D][D]
    f16*   Qp   = (f16*)(ws + MB(24));     // [NT][D] (dead after scores)
    f16*   Af   = (f16*)(ws + MB(32));     // [NT][NT] f16 scores -> softmax A
    f16*   RHt  = (f16*)(ws + MB(64));     // [D][NT]
    f16*   Y1h  = (f16*)(ws + MB(72));     // [NT][D]
    f16*   hb   = (f16*)(ws + MB(24));     // over Qp (dead)
    float* outF = (float*)d_out;           // [D][NT]

    // 1. Weight prep: Wq/Wk/Wv convert + Wo transpose.
    prep_w<<<4096, 256, 0, stream>>>(W[0], W[1], W[2], W[3],
                                     Wqh, Wkh, Wvh, Wot, D);

    // 2. X-transpose ++ W4/W5 transposes ++ tiny GT/HT GEMMs (independent).
    prepx_tiny<<<6656, 256, 0, stream>>>(X, Xth, W[4], W[5], W4t, W5t,
                                         Wkh, Wqh, GT, Wot, Wvh, HT, D, NT);

    // 3. Q' = Xt*G^T (PF2).
    midq<<<512, 256, 0, stream>>>(Xth, GT, Qp);

    // 4. Scores (lower triangle, 128² dbuf-counted).
    scores_tri<<<528, 256, 0, stream>>>(Qp, Xth, Af);

    // 5. Softmax ++ RHt = HT*Xt^T (complementary pipes, fused).
    softmax_midrh<<<4352, 256, 0, stream>>>(Af, NT, HT, Xth, RHt);

    // 6. Y1 = Xt + A@RH (causal-K truncation, CU-pair-balanced, PF2).
    gemm_nar<2, true><<<512, 256, 0, stream>>>(
        Af, RHt, nullptr, Y1h, Xth, NT, D, NT, NT);

    // 7. h = relu(Y1 @ mlp_in).
    gemm_nar<3, false><<<512, 256, 0, stream>>>(
        Y1h, W4t, nullptr, hb, nullptr, NT, D, D, D);

    // 8. out = (Y1 + h @ mlp_out)^T.
    gemm_nar<4, false><<<512, 256, 0, stream>>>(
        hb, W5t, outF, nullptr, Y1h, NT, D, D, D);
}

// Round 8
// 226.821 us; speedup vs baseline: 1.1434x; 1.0784x over previous
//
#include <hip/hip_runtime.h>
#include <stdint.h>
#include <stddef.h>

using f16 = _Float16;
typedef __attribute__((ext_vector_type(8))) _Float16 f16x8;
typedef __attribute__((ext_vector_type(4))) float f32x4;

// ---------------------------------------------------------------------------
__device__ __forceinline__ void async_copy16(const f16* g, f16* l) {
    __builtin_amdgcn_global_load_lds(
        (const __attribute__((address_space(1))) void*)g,
        (__attribute__((address_space(3))) void*)l, 16, 0, 0);
}

template <int N>
__device__ __forceinline__ void wait_vmcnt() {
    if constexpr (N == 0)       asm volatile("s_waitcnt vmcnt(0)" ::: "memory");
    else if constexpr (N == 6)  asm volatile("s_waitcnt vmcnt(6)" ::: "memory");
    else if constexpr (N == 8)  asm volatile("s_waitcnt vmcnt(8)" ::: "memory");
}

__device__ __forceinline__ void hard_barrier() {
    __builtin_amdgcn_sched_barrier(0);
    __builtin_amdgcn_s_barrier();
    __builtin_amdgcn_sched_barrier(0);
}

// ---------------------------------------------------------------------------
// Weight prep, 6144 blocks: z<3 f16 convert (Wq,Wk,Wv), z>=3 f16 transpose
// (Wo, mlp_in, mlp_out).
__global__ __launch_bounds__(256)
void prep_w(const float* __restrict__ w0, const float* __restrict__ w1,
            const float* __restrict__ w2, const float* __restrict__ w3,
            const float* __restrict__ w4, const float* __restrict__ w5,
            f16* o0, f16* o1, f16* o2, f16* o3, f16* o4, f16* o5, int D) {
    __shared__ float tile[32][33];
    const int tx = threadIdx.x & 31, ty = threadIdx.x >> 5;
    const int b = blockIdx.x;
    const int z = b >> 10, r = b & 1023;
    const float* in = z == 0 ? w0 : z == 1 ? w1 : z == 2 ? w2 : z == 3 ? w3 : z == 4 ? w4 : w5;
    f16* out = z == 0 ? o0 : z == 1 ? o1 : z == 2 ? o2 : z == 3 ? o3 : z == 4 ? o4 : o5;
    const int c0 = (r & 31) * 32, r0 = (r >> 5) * 32;
    if (z < 3) {
#pragma unroll
        for (int j = 0; j < 4; j++) {
            size_t idx = (size_t)(r0 + ty + j * 8) * D + c0 + tx;
            out[idx] = (f16)in[idx];
        }
    } else {
#pragma unroll
        for (int j = 0; j < 4; j++)
            tile[ty + j * 8][tx] = in[(size_t)(r0 + ty + j * 8) * D + c0 + tx];
        __syncthreads();
#pragma unroll
        for (int j = 0; j < 4; j++)
            out[(size_t)(c0 + ty + j * 8) * D + r0 + tx] = (f16)tile[tx][ty + j * 8];
    }
}

// ---------------------------------------------------------------------------
// 64x64x128-step fp16 GEMM body, double-buffered+swizzled (tiny stage only).
__device__ __forceinline__ void body64db(
    f16* lds, const f16* __restrict__ A, const f16* __restrict__ B,
    f16* __restrict__ Ch, int m0, int n0, int N, int K, int lda) {
    const int t = threadIdx.x;
    const int lane = t & 63, wave = t >> 6;
    const int wm = (wave >> 1) * 32, wn = (wave & 1) * 32;
    const int lm = lane & 15, lq = lane >> 4;
    const int srow = t >> 2;
    const int gs = ((t & 3) ^ ((srow >> 1) & 3)) * 8;
    const int rs = (lq ^ ((lm >> 1) & 3)) * 8;

    auto stage = [&](f16* buf, int k0) {
#pragma unroll
        for (int r = 0; r < 4; r++)
            async_copy16(A + (size_t)(m0 + srow) * lda + k0 + r * 32 + gs,
                         buf + r * 2048 + t * 8);
#pragma unroll
        for (int r = 0; r < 4; r++)
            async_copy16(B + (size_t)(n0 + srow) * K + k0 + r * 32 + gs,
                         buf + 8192 + r * 2048 + t * 8);
    };

    f32x4 acc[2][2] = {};
    stage(lds, 0);
    __syncthreads();
    int cur = 0;
    for (int k0 = 0; k0 < K; k0 += 128) {
        f16* cb = lds + cur * 16384;
        if (k0 + 128 < K) stage(lds + (cur ^ 1) * 16384, k0 + 128);
#pragma unroll
        for (int kk = 0; kk < 4; kk++) {
            f16x8 af[2], bf[2];
#pragma unroll
            for (int i = 0; i < 2; i++)
                af[i] = *(const f16x8*)&cb[kk * 2048 + (wm + i * 16 + lm) * 32 + rs];
#pragma unroll
            for (int j = 0; j < 2; j++)
                bf[j] = *(const f16x8*)&cb[8192 + kk * 2048 + (wn + j * 16 + lm) * 32 + rs];
#pragma unroll
            for (int i = 0; i < 2; i++)
#pragma unroll
                for (int j = 0; j < 2; j++)
                    acc[i][j] = __builtin_amdgcn_mfma_f32_16x16x32_f16(
                        af[i], bf[j], acc[i][j], 0, 0, 0);
        }
        __syncthreads();
        cur ^= 1;
    }

#pragma unroll
    for (int i = 0; i < 2; i++) {
        const int row = m0 + wm + i * 16 + lq * 4;
#pragma unroll
        for (int j = 0; j < 2; j++) {
            const int col = n0 + wn + j * 16 + lm;
            f32x4 v = acc[i][j];
#pragma unroll
            for (int r = 0; r < 4; r++)
                Ch[(size_t)(row + r) * N + col] = (f16)v[r];
        }
    }
}

// ---------------------------------------------------------------------------
// Fused: X-transpose (blocks 0..4095) ++ tiny GT/HT GEMMs (4096..4607).
__global__ __launch_bounds__(256, 2)
void prepx_tiny(const float* __restrict__ X, f16* __restrict__ Xth,
                const f16* Wkh, const f16* Wqh, f16* GT,
                const f16* Wot, const f16* Wvh, f16* HT, int D, int NT) {
    __shared__ alignas(16) f16 smem[32768];
    int b = blockIdx.x;
    if (b < 4096) {
        float* tile = (float*)smem;  // [32][33]
        const int tx = threadIdx.x & 31, ty = threadIdx.x >> 5;
        const int c0 = (b & 127) * 32, r0 = (b >> 7) * 32;  // c over NT, r over D
#pragma unroll
        for (int j = 0; j < 4; j++)
            tile[(ty + j * 8) * 33 + tx] = X[(size_t)(r0 + ty + j * 8) * NT + c0 + tx];
        __syncthreads();
#pragma unroll
        for (int j = 0; j < 4; j++)
            Xth[(size_t)(c0 + ty + j * 8) * D + r0 + tx] = (f16)tile[tx * 33 + ty + j * 8];
        return;
    }
    b -= 4096;  // 0..511
    if (b < 256)
        body64db(smem, Wkh, Wqh, GT, (b >> 4) * 64, (b & 15) * 64, 1024, 1024, 1024);
    else {
        const int r = b - 256;
        body64db(smem, Wot, Wvh, HT, (r >> 4) * 64, (r & 15) * 64, 1024, 1024, 1024);
    }
}

// ---------------------------------------------------------------------------
// Causal softmax over f16 A rows IN-PLACE (pitch N).
__global__ __launch_bounds__(256)
void softmax_rows(f16* __restrict__ A, int N) {
    const int row = blockIdx.x, len = row + 1;
    const int lim = ((row >> 7) + 1) << 7;
    f16* a = A + (size_t)row * N;
    __shared__ float red[256];
    const int t = threadIdx.x;

    float v[16];
    float mx = -1e30f;
#pragma unroll
    for (int j = 0; j < 2; j++) {
        const int c = (t + j * 256) * 8;
        if (c < len) {
            f16x8 x = *(const f16x8*)(a + c);
#pragma unroll
            for (int e = 0; e < 8; e++) {
                float f = (c + e < len) ? (float)x[e] : -1e30f;
                v[j * 8 + e] = f;
                mx = fmaxf(mx, f);
            }
        } else {
#pragma unroll
            for (int e = 0; e < 8; e++) v[j * 8 + e] = -1e30f;
        }
    }
    red[t] = mx; __syncthreads();
    for (int o = 128; o > 0; o >>= 1) { if (t < o) red[t] = fmaxf(red[t], red[t + o]); __syncthreads(); }
    mx = red[0]; __syncthreads();

    float sum = 0.f;
#pragma unroll
    for (int k = 0; k < 16; k++) {
        float e = (v[k] > -1e29f) ? __expf(v[k] - mx) : 0.0f;
        v[k] = e;
        sum += e;
    }
    red[t] = sum; __syncthreads();
    for (int o = 128; o > 0; o >>= 1) { if (t < o) red[t] += red[t + o]; __syncthreads(); }
    const float inv = 1.0f / red[0];
#pragma unroll
    for (int j = 0; j < 2; j++) {
        const int c = (t + j * 256) * 8;
        if (c < lim) {
            f16x8 o8;
#pragma unroll
            for (int e = 0; e < 8; e++) o8[e] = (f16)(v[j * 8 + e] * inv);
            *(f16x8*)(a + c) = o8;
        }
    }
}

// ---------------------------------------------------------------------------
// Swizzle (proven, conflicts 0): LDS [kk][row][32] f16; k-group g of row r
// stored at slot g ^ ((r>>1)&3); applied to global source col (gs) and
// ds_read slot (rs); gload_lds dest stays linear.
// ---------------------------------------------------------------------------

// 128x128 tile, BK=64, 4 waves each 64x64 (acc 4x4). Double-buffered 64 KB,
// counted vmcnt(8) (R5-proven). MODE 0 only.
__device__ __forceinline__ void body128sq(
    f16* lds, const f16* __restrict__ A, const f16* __restrict__ B,
    f16* __restrict__ Ch, int m0, int n0, int N, int K, int lda) {
    constexpr int BUF = 16384;
    const int t = threadIdx.x;
    const int lane = t & 63, wave = t >> 6;
    const int wm = (wave >> 1) * 64, wn = (wave & 1) * 64;
    const int lm = lane & 15, lq = lane >> 4;
    const int srow = t >> 2;
    const int gs = ((t & 3) ^ ((srow >> 1) & 3)) * 8;
    const int rs = (lq ^ ((lm >> 1) & 3)) * 8;

    f32x4 acc[4][4] = {};

    auto stage = [&](f16* buf, int k0) {
#pragma unroll
        for (int r = 0; r < 4; r++)
            async_copy16(A + (size_t)(m0 + (r & 1) * 64 + srow) * lda + k0 + (r >> 1) * 32 + gs,
                         buf + r * 2048 + t * 8);
#pragma unroll
        for (int r = 0; r < 4; r++)
            async_copy16(B + (size_t)(n0 + (r & 1) * 64 + srow) * K + k0 + (r >> 1) * 32 + gs,
                         buf + 8192 + r * 2048 + t * 8);
    };

    auto compute = [&](const f16* cb) {
#pragma unroll
        for (int kk = 0; kk < 2; kk++) {
            f16x8 af[4], bf[4];
#pragma unroll
            for (int i = 0; i < 4; i++)
                af[i] = *(const f16x8*)&cb[kk * 4096 + (wm + i * 16 + lm) * 32 + rs];
#pragma unroll
            for (int j = 0; j < 4; j++)
                bf[j] = *(const f16x8*)&cb[8192 + kk * 4096 + (wn + j * 16 + lm) * 32 + rs];
#pragma unroll
            for (int i = 0; i < 4; i++)
#pragma unroll
                for (int j = 0; j < 4; j++)
                    acc[i][j] = __builtin_amdgcn_mfma_f32_16x16x32_f16(
                        af[i], bf[j], acc[i][j], 0, 0, 0);
        }
    };

    const int NS = K >> 6;
    stage(lds, 0);
    for (int s = 0; s < NS; s++) {
        if (s + 1 < NS) {
            stage(lds + ((s + 1) & 1) * BUF, (s + 1) << 6);
            wait_vmcnt<8>();
        } else {
            wait_vmcnt<0>();
        }
        hard_barrier();
        compute(lds + (s & 1) * BUF);
        if (s + 1 < NS) hard_barrier();
    }

#pragma unroll
    for (int i = 0; i < 4; i++) {
        const int row = m0 + wm + i * 16 + lq * 4;
#pragma unroll
        for (int j = 0; j < 4; j++) {
            const int col = n0 + wn + j * 16 + lm;
            f32x4 v = acc[i][j];
#pragma unroll
            for (int r = 0; r < 4; r++)
                Ch[(size_t)(row + r) * N + col] = (f16)v[r];
        }
    }
}

// ---------------------------------------------------------------------------
// 128x64 tile, BK=64, counted DOUBLE-buffer: 2 x 24 KB = 48 KB -> 3
// blocks/CU (the untested cell: T4 counted wait + 3-block cross-hiding).
// Per iter: stage(s+1) -> vmcnt(6) (tile s landed, s+1 in flight) ->
// barrier -> compute(s) -> barrier (protects buf re-staged next iter).
// MODE 0: Ch = f16(acc)
// MODE 2: Ch = f16(acc + residH)
// MODE 3: Ch = f16(relu(acc))
// MODE 4: Cf[col*M + row] = acc + residH[row*N + col]  (transposed store)
template <int MODE>
__device__ __forceinline__ void body_nar2(
    f16* lds, const f16* __restrict__ A, const f16* __restrict__ B,
    float* __restrict__ Cf, f16* __restrict__ Ch, const f16* __restrict__ resid,
    int m0, int n0, int M, int N, int K, int lda, int Keff) {
    constexpr int ASZ = 128 * 64;   // 8192 f16
    constexpr int SSZ = ASZ + 64 * 64;  // 12288 f16 = 24 KB per buffer
    const int t = threadIdx.x;
    const int lane = t & 63, wave = t >> 6;
    const int wm = (wave >> 1) * 64, wn = (wave & 1) * 32;
    const int lm = lane & 15, lq = lane >> 4;
    const int srow = t >> 2;
    const int gs = ((t & 3) ^ ((srow >> 1) & 3)) * 8;
    const int rs = (lq ^ ((lm >> 1) & 3)) * 8;

    f32x4 acc[4][2] = {};

    auto stage = [&](f16* buf, int k0) {
        // 6 gload_lds per wave (4 A + 2 B).
#pragma unroll
        for (int r = 0; r < 4; r++)
            async_copy16(A + (size_t)(m0 + (r & 1) * 64 + srow) * lda + k0 + (r >> 1) * 32 + gs,
                         buf + r * 2048 + t * 8);
#pragma unroll
        for (int r = 0; r < 2; r++)
            async_copy16(B + (size_t)(n0 + srow) * K + k0 + r * 32 + gs,
                         buf + ASZ + r * 2048 + t * 8);
    };

    auto compute = [&](const f16* cb) {
#pragma unroll
        for (int kk = 0; kk < 2; kk++) {
            f16x8 af[4], bf[2];
#pragma unroll
            for (int i = 0; i < 4; i++)
                af[i] = *(const f16x8*)&cb[kk * 4096 + (wm + i * 16 + lm) * 32 + rs];
#pragma unroll
            for (int j = 0; j < 2; j++)
                bf[j] = *(const f16x8*)&cb[ASZ + kk * 2048 + (wn + j * 16 + lm) * 32 + rs];
#pragma unroll
            for (int i = 0; i < 4; i++)
#pragma unroll
                for (int j = 0; j < 2; j++)
                    acc[i][j] = __builtin_amdgcn_mfma_f32_16x16x32_f16(
                        af[i], bf[j], acc[i][j], 0, 0, 0);
        }
    };

    stage(lds, 0);
    const int NS = Keff >> 6;
    for (int s = 0; s < NS; s++) {
        if (s + 1 < NS) {
            stage(lds + ((s + 1) & 1) * SSZ, (s + 1) << 6);
            wait_vmcnt<6>();   // tile s landed; tile s+1 stays in flight
        } else {
            wait_vmcnt<0>();
        }
        hard_barrier();
        compute(lds + (s & 1) * SSZ);
        hard_barrier();        // all waves done reading before next re-stage
    }

#pragma unroll
    for (int i = 0; i < 4; i++) {
        const int row = m0 + wm + i * 16 + lq * 4;
#pragma unroll
        for (int j = 0; j < 2; j++) {
            const int col = n0 + wn + j * 16 + lm;
            f32x4 v = acc[i][j];
#pragma unroll
            for (int r = 0; r < 4; r++) {
                if (MODE == 0) {
                    Ch[(size_t)(row + r) * N + col] = (f16)v[r];
                } else if (MODE == 2) {
                    float o = v[r] + (float)resid[(size_t)(row + r) * N + col];
                    Ch[(size_t)(row + r) * N + col] = (f16)o;
                } else if (MODE == 3) {
                    Ch[(size_t)(row + r) * N + col] = (f16)fmaxf(v[r], 0.0f);
                } else {
                    float o = v[r] + (float)resid[(size_t)(row + r) * N + col];
                    Cf[(size_t)col * M + (row + r)] = o;
                }
            }
        }
    }
}

// ---------------------------------------------------------------------------
// Q' = Xt*G^T [4096,1024,1024], 128x64 tiles, 512 blocks, 3/CU.
__global__ __launch_bounds__(256, 3)
void midq(const f16* Xth, const f16* GT, f16* Qp) {
    __shared__ alignas(16) f16 smem[24576];
    const int x = blockIdx.x & 7, s = blockIdx.x >> 3;  // 0..63
    const int m = x + 8 * (s >> 4), n = s & 15;
    body_nar2<0>(smem, Xth, GT, nullptr, Qp, nullptr,
                 m * 128, n * 64, 4096, 1024, 1024, 1024, 1024);
}

// ---------------------------------------------------------------------------
// Fused: scores (lower triangle, blocks 0..527) ++ RHt = HT*Xt^T (528..783).
// midrh blocks backfill into the long scores launch (R5-proven).
__global__ __launch_bounds__(256, 2)
void scores_midrh(const f16* Qp, const f16* Xth, f16* Af,
                  const f16* HT, f16* RHt) {
    __shared__ alignas(16) f16 smem[32768];
    int b = blockIdx.x;
    if (b < 528) {
        const int x = b & 7;
        int s = b >> 3;  // 0..65
        int m = 0, n = 0;
#pragma unroll
        for (int q = 3; q >= 0; q--) {
            const int mm = 8 * q + ((q & 1) ? 7 - x : x);
            if (s < mm + 1) { m = mm; n = s; break; }
            s -= mm + 1;
        }
        body128sq(smem, Qp, Xth, Af, m * 128, n * 128, 4096, 1024, 1024);
    } else {
        const int r = b - 528;  // 0..255
        const int x = r & 7;
        const int s = r >> 3;   // 0..31
        const int n = x + 8 * (s >> 3), m = s & 7;
        body128sq(smem, HT, Xth, RHt, m * 128, n * 128, 4096, 1024, 1024);
    }
}

// Narrow GEMMs [M=4096, N=1024], 128x64 tiles, 512 blocks, 3/CU.
// CAUSAL: q-permutation {3,2,0,1} + zigzag balances K-work across CUs.
template <int MODE, bool CAUSAL_K>
__global__ __launch_bounds__(256, 3)
void gemm_nar(const f16* __restrict__ A, const f16* __restrict__ B,
              float* __restrict__ Cf, f16* __restrict__ Ch,
              const f16* __restrict__ resid, int M, int N, int K, int lda) {
    __shared__ alignas(16) f16 smem[24576];
    const int x = blockIdx.x & 7, s = blockIdx.x >> 3;  // s in 0..63
    const int qs = s >> 4, n = s & 15;
    int m;
    if (CAUSAL_K) {
        const int q = (qs == 0) ? 3 : (qs == 1) ? 2 : (qs == 2) ? 0 : 1;
        m = 8 * q + ((q & 1) ? 7 - x : x);
    } else {
        m = x + 8 * qs;
    }
    const int m0 = m * 128, n0 = n * 64;
    int Keff = K;
    if (CAUSAL_K) {
        Keff = m0 + 128;
        if (Keff > K) Keff = K;
    }
    body_nar2<MODE>(smem, A, B, Cf, Ch, resid,
                    m0, n0, M, N, K, lda, Keff);
}

// ---------------------------------------------------------------------------
extern "C" void kernel_launch(void* const* d_in, const int* in_sizes, int n_in,
                              void* d_out, int out_size, void* d_ws, size_t ws_size,
                              hipStream_t stream) {
    const int D = 1024, NT = 4096;
    const float* X = (const float*)d_in[0];
    const float* W[6] = {(const float*)d_in[1], (const float*)d_in[2],
                         (const float*)d_in[3], (const float*)d_in[4],
                         (const float*)d_in[5], (const float*)d_in[6]};
    char* ws = (char*)d_ws;
    auto MB = [](size_t x) { return x << 20; };

    // Workspace (80 MB peak):
    f16*   Xth  = (f16*)(ws + MB(0));      // [NT][D] (also f16 residual)
    f16*   Wqh  = (f16*)(ws + MB(8));
    f16*   Wkh  = (f16*)(ws + MB(10));
    f16*   Wvh  = (f16*)(ws + MB(12));
    f16*   Wot  = (f16*)(ws + MB(14));
    f16*   W4t  = (f16*)(ws + MB(16));
    f16*   W5t  = (f16*)(ws + MB(18));
    f16*   GT   = (f16*)(ws + MB(20));     // [D][D]
    f16*   HT   = (f16*)(ws + MB(22));     // [D][D]
    f16*   Qp   = (f16*)(ws + MB(24));     // [NT][D] (dead after scores)
    f16*   Af   = (f16*)(ws + MB(32));     // [NT][NT] f16 scores -> softmax A
    f16*   RHt  = (f16*)(ws + MB(64));     // [D][NT]
    f16*   Y1h  = (f16*)(ws + MB(72));     // [NT][D]
    f16*   hb   = (f16*)(ws + MB(24));     // over Qp (dead)
    float* outF = (float*)d_out;           // [D][NT]

    // 1. Weight prep (convert + transpose).
    prep_w<<<6144, 256, 0, stream>>>(W[0], W[1], W[2], W[3], W[4], W[5],
                                     Wqh, Wkh, Wvh, Wot, W4t, W5t, D);

    // 2. X-transpose ++ GT = Wk*Wq^T ++ HT = Wo^T*Wv^T (fused, independent).
    prepx_tiny<<<4608, 256, 0, stream>>>(X, Xth, Wkh, Wqh, GT, Wot, Wvh, HT,
                                         D, NT);

    // 3. Q' = Xt*G^T (counted dbuf, 3/CU).
    midq<<<512, 256, 0, stream>>>(Xth, GT, Qp);

    // 4. Scores (lower triangle) ++ RHt = HT*Xt^T (fused, R5-proven).
    scores_midrh<<<784, 256, 0, stream>>>(Qp, Xth, Af, HT, RHt);

    // 5. Softmax in-place on f16 A (pitch NT).
    softmax_rows<<<NT, 256, 0, stream>>>(Af, NT);

    // 6. Y1 = Xt + A@RH (causal-K truncation, CU-pair-balanced, 3/CU).
    gemm_nar<2, true><<<512, 256, 0, stream>>>(
        Af, RHt, nullptr, Y1h, Xth, NT, D, NT, NT);

    // 7. h = relu(Y1 @ mlp_in).
    gemm_nar<3, false><<<512, 256, 0, stream>>>(
        Y1h, W4t, nullptr, hb, nullptr, NT, D, D, D);

    // 8. out = (Y1 + h @ mlp_out)^T.
    gemm_nar<4, false><<<512, 256, 0, stream>>>(
        hb, W5t, outF, nullptr, Y1h, NT, D, D, D);
}